// Round 2
// baseline (432.376 us; speedup 1.0000x reference)
//
#include <hip/hip_runtime.h>
#include <hip/hip_bf16.h>

// Problem constants
#define BDIM 8
#define TDIM 256
#define UDIM 64
#define HDIM 640
#define VDIM 1024
// M = B*T*U = 131072, K = 640, N = 1024

#define MDIM (BDIM * TDIM * UDIM)

typedef __attribute__((ext_vector_type(8))) short short8;   // 8 bf16 (16B)
typedef __attribute__((ext_vector_type(4))) float f32x4;

__device__ __forceinline__ ushort f2bf(float x) {
    union { float f; unsigned int u; } v; v.f = x;
    unsigned int r = (v.u + 0x7fffu + ((v.u >> 16) & 1u)) >> 16;  // RNE
    return (ushort)r;
}

// Prep 1: convert W (V x H fp32, row-major [v][h]) to bf16 in workspace.
__global__ void cvt_w_kernel(const float* __restrict__ W, ushort* __restrict__ Wb) {
    int i = (blockIdx.x * 256 + threadIdx.x) * 4;   // grid sized exactly
    f32x4 w = *(const f32x4*)(W + i);
    ushort4 o;
    o.x = f2bf(w[0]); o.y = f2bf(w[1]); o.z = f2bf(w[2]); o.w = f2bf(w[3]);
    *(ushort4*)(Wb + i) = o;
}

// Prep 2: materialize h[m][k] = relu(f[b][t][k] + p[b][u][k]) as bf16.
// m = b*T*U + t*U + u. 32 rows per block, 10 chunk-iters per thread.
// Lanes 0..7 cover 8 consecutive 16B chunks (128B contiguous) of one row.
__global__ __launch_bounds__(256) void build_h_kernel(
    const float* __restrict__ f, const float* __restrict__ p,
    ushort* __restrict__ h)
{
    const int tid = threadIdx.x;
    const int row = (blockIdx.x << 5) + (tid >> 3);   // global m
    const int j0  = tid & 7;
    const int b = row >> 14;                // / (T*U)
    const int t = (row >> 6) & (TDIM - 1);
    const int u = row & (UDIM - 1);
    const float* frow = f + (size_t)(b * TDIM + t) * HDIM;
    const float* prow = p + (size_t)(b * UDIM + u) * HDIM;
    ushort* hrow = h + (size_t)row * HDIM;
    #pragma unroll
    for (int it = 0; it < HDIM / 64; ++it) {
        const int k = (j0 + it * 8) * 8;
        f32x4 f0 = *(const f32x4*)(frow + k);
        f32x4 f1 = *(const f32x4*)(frow + k + 4);
        f32x4 p0 = *(const f32x4*)(prow + k);
        f32x4 p1 = *(const f32x4*)(prow + k + 4);
        short8 hv;
        #pragma unroll
        for (int e = 0; e < 4; ++e) {
            float a0 = fmaxf(f0[e] + p0[e], 0.0f);
            float a1 = fmaxf(f1[e] + p1[e], 0.0f);
            hv[e]     = (short)f2bf(a0);
            hv[e + 4] = (short)f2bf(a1);
        }
        *(short8*)(hrow + k) = hv;
    }
}

// Pure bf16 GEMM, m97 structure: 128x128 tile, BK=64, 4 waves (2x2),
// 16x16x32 bf16 MFMA, both operands staged via global_load_lds (16B) with
// pre-swizzled global source addresses; LDS slot = chunk ^ (row&7).
__global__ __launch_bounds__(256) void hgemm_kernel(
    const ushort* __restrict__ h,     // (M,H) bf16
    const ushort* __restrict__ Wb,    // (V,H) bf16
    const float* __restrict__ bias,   // (V)
    float* __restrict__ out)          // (M,V) fp32
{
    __shared__ ushort Alds[128 * 64];  // 16 KB
    __shared__ ushort Blds[128 * 64];  // 16 KB

    const int tid  = threadIdx.x;
    const int lane = tid & 63;
    const int wave = tid >> 6;
    const int wm   = wave >> 1;
    const int wn   = wave & 1;

    // Bijective XCD swizzle: 8192 blocks, 8 XCDs. One XCD's consecutive work
    // items walk the 8 ntiles of one mtile -> 160KB h-panel L2-reused 8x,
    // Wb (1.25MB) stays L2-resident per XCD.
    const int bid   = blockIdx.x;
    const int work  = (bid & 7) * 1024 + (bid >> 3);
    const int mtile = work >> 3;
    const int ntile = work & 7;
    const int m0 = mtile * 128;
    const int v0 = ntile * 128;

    const ushort* hbase  = h  + (size_t)m0 * HDIM;
    const ushort* wbbase = Wb + (size_t)v0 * HDIM;

    f32x4 acc[4][4];
    #pragma unroll
    for (int i = 0; i < 4; ++i)
        #pragma unroll
        for (int j = 0; j < 4; ++j)
            acc[i][j] = (f32x4)0.0f;

    for (int kt = 0; kt < HDIM / 64; ++kt) {
        const int k0 = kt * 64;
        __syncthreads();   // previous iteration's LDS reads complete

        // stage A tile: 128 (m) x 64 (k), 1024 x 16B chunks
        #pragma unroll
        for (int it = 0; it < 4; ++it) {
            const int c   = it * 256 + tid;
            const int row = c >> 3;
            const int j   = c & 7;
            const ushort* src = hbase + row * HDIM + k0 + ((j ^ (row & 7)) << 3);
            __builtin_amdgcn_global_load_lds(
                (const __attribute__((address_space(1))) void*)src,
                (__attribute__((address_space(3))) void*)(&Alds[(it * 256 + wave * 64) * 8]),
                16, 0, 0);
        }
        // stage B tile: 128 (v) x 64 (k)
        #pragma unroll
        for (int it = 0; it < 4; ++it) {
            const int c   = it * 256 + tid;
            const int row = c >> 3;
            const int j   = c & 7;
            const ushort* src = wbbase + row * HDIM + k0 + ((j ^ (row & 7)) << 3);
            __builtin_amdgcn_global_load_lds(
                (const __attribute__((address_space(1))) void*)src,
                (__attribute__((address_space(3))) void*)(&Blds[(it * 256 + wave * 64) * 8]),
                16, 0, 0);
        }

        __syncthreads();   // drains vmcnt + lgkmcnt

        #pragma unroll
        for (int ks = 0; ks < 2; ++ks) {
            short8 afr[4], bfr[4];
            #pragma unroll
            for (int mi = 0; mi < 4; ++mi) {
                const int r = wm * 64 + mi * 16 + (lane & 15);
                const int j = ks * 4 + (lane >> 4);
                afr[mi] = *(const short8*)(&Alds[(r * 8 + (j ^ (r & 7))) * 8]);
            }
            #pragma unroll
            for (int ni = 0; ni < 4; ++ni) {
                const int r = wn * 64 + ni * 16 + (lane & 15);
                const int j = ks * 4 + (lane >> 4);
                bfr[ni] = *(const short8*)(&Blds[(r * 8 + (j ^ (r & 7))) * 8]);
            }
            #pragma unroll
            for (int mi = 0; mi < 4; ++mi)
                #pragma unroll
                for (int ni = 0; ni < 4; ++ni)
                    acc[mi][ni] = __builtin_amdgcn_mfma_f32_16x16x32_bf16(
                        afr[mi], bfr[ni], acc[mi][ni], 0, 0, 0);
        }
    }

    // epilogue: C/D layout col = lane&15, row = (lane>>4)*4 + reg
    #pragma unroll
    for (int ni = 0; ni < 4; ++ni) {
        const int col = v0 + wn * 64 + ni * 16 + (lane & 15);
        const float bv = bias[col];
        #pragma unroll
        for (int mi = 0; mi < 4; ++mi) {
            const int rbase = m0 + wm * 64 + mi * 16 + ((lane >> 4) << 2);
            #pragma unroll
            for (int reg = 0; reg < 4; ++reg) {
                out[(size_t)(rbase + reg) * VDIM + col] = acc[mi][ni][reg] + bv;
            }
        }
    }
}

// ---------------- fallback fused kernel (round-1 verified) ----------------
template <bool USE_WB>
__global__ __launch_bounds__(256) void joint_gemm_kernel(
    const float* __restrict__ f, const float* __restrict__ p,
    const float* __restrict__ Wf, const ushort* __restrict__ Wb,
    const float* __restrict__ bias, float* __restrict__ out)
{
    __shared__ ushort Alds[128 * 64];
    __shared__ ushort Blds[128 * 64];

    const int tid  = threadIdx.x;
    const int lane = tid & 63;
    const int wave = tid >> 6;
    const int wm   = wave >> 1;
    const int wn   = wave & 1;

    const int bid   = blockIdx.x;
    const int work  = (bid & 7) * 1024 + (bid >> 3);
    const int mtile = work >> 3;
    const int ntile = work & 7;
    const int m0 = mtile * 128;
    const int v0 = ntile * 128;

    const int b  = m0 >> 14;
    const int t0 = (m0 >> 6) & (TDIM - 1);

    const float*  fbase = f + (size_t)(b * TDIM + t0) * HDIM;
    const float*  pbase = p + (size_t)b * UDIM * HDIM;
    const ushort* wbbase = Wb + (size_t)v0 * HDIM;
    const float*  wfbase = Wf + (size_t)v0 * HDIM;

    f32x4 acc[4][4];
    #pragma unroll
    for (int i = 0; i < 4; ++i)
        #pragma unroll
        for (int j = 0; j < 4; ++j)
            acc[i][j] = (f32x4)0.0f;

    for (int kt = 0; kt < HDIM / 64; ++kt) {
        const int k0 = kt * 64;
        __syncthreads();

        if (USE_WB) {
            #pragma unroll
            for (int it = 0; it < 4; ++it) {
                const int c   = it * 256 + tid;
                const int row = c >> 3;
                const int j   = c & 7;
                const ushort* src = wbbase + row * HDIM + k0 + ((j ^ (row & 7)) << 3);
                __builtin_amdgcn_global_load_lds(
                    (const __attribute__((address_space(1))) void*)src,
                    (__attribute__((address_space(3))) void*)(&Blds[(it * 256 + wave * 64) * 8]),
                    16, 0, 0);
            }
        } else {
            #pragma unroll
            for (int it = 0; it < 4; ++it) {
                const int c   = it * 256 + tid;
                const int row = c >> 3;
                const int j   = c & 7;
                const float* wp = wfbase + row * HDIM + k0 + j * 8;
                f32x4 w0 = *(const f32x4*)wp;
                f32x4 w1 = *(const f32x4*)(wp + 4);
                short8 wv;
                #pragma unroll
                for (int e = 0; e < 4; ++e) {
                    wv[e]     = (short)f2bf(w0[e]);
                    wv[e + 4] = (short)f2bf(w1[e]);
                }
                *(short8*)(&Blds[(row * 8 + (j ^ (row & 7))) * 8]) = wv;
            }
        }

        #pragma unroll
        for (int it = 0; it < 4; ++it) {
            const int c   = it * 256 + tid;
            const int row = c >> 3;
            const int j   = c & 7;
            const float* fp_ = fbase + (row >> 6) * HDIM + k0 + j * 8;
            const float* pp_ = pbase + (row & 63) * HDIM + k0 + j * 8;
            f32x4 f0 = *(const f32x4*)fp_;
            f32x4 f1 = *(const f32x4*)(fp_ + 4);
            f32x4 p0 = *(const f32x4*)pp_;
            f32x4 p1 = *(const f32x4*)(pp_ + 4);
            short8 hv;
            #pragma unroll
            for (int e = 0; e < 4; ++e) {
                float a0 = fmaxf(f0[e] + p0[e], 0.0f);
                float a1 = fmaxf(f1[e] + p1[e], 0.0f);
                hv[e]     = (short)f2bf(a0);
                hv[e + 4] = (short)f2bf(a1);
            }
            *(short8*)(&Alds[(row * 8 + (j ^ (row & 7))) * 8]) = hv;
        }

        __syncthreads();

        #pragma unroll
        for (int ks = 0; ks < 2; ++ks) {
            short8 afr[4], bfr[4];
            #pragma unroll
            for (int mi = 0; mi < 4; ++mi) {
                const int r = wm * 64 + mi * 16 + (lane & 15);
                const int j = ks * 4 + (lane >> 4);
                afr[mi] = *(const short8*)(&Alds[(r * 8 + (j ^ (r & 7))) * 8]);
            }
            #pragma unroll
            for (int ni = 0; ni < 4; ++ni) {
                const int r = wn * 64 + ni * 16 + (lane & 15);
                const int j = ks * 4 + (lane >> 4);
                bfr[ni] = *(const short8*)(&Blds[(r * 8 + (j ^ (r & 7))) * 8]);
            }
            #pragma unroll
            for (int mi = 0; mi < 4; ++mi)
                #pragma unroll
                for (int ni = 0; ni < 4; ++ni)
                    acc[mi][ni] = __builtin_amdgcn_mfma_f32_16x16x32_bf16(
                        afr[mi], bfr[ni], acc[mi][ni], 0, 0, 0);
        }
    }

    #pragma unroll
    for (int ni = 0; ni < 4; ++ni) {
        const int col = v0 + wn * 64 + ni * 16 + (lane & 15);
        const float bv = bias[col];
        #pragma unroll
        for (int mi = 0; mi < 4; ++mi) {
            const int rbase = m0 + wm * 64 + mi * 16 + ((lane >> 4) << 2);
            #pragma unroll
            for (int reg = 0; reg < 4; ++reg) {
                out[(size_t)(rbase + reg) * VDIM + col] = acc[mi][ni][reg] + bv;
            }
        }
    }
}

extern "C" void kernel_launch(void* const* d_in, const int* in_sizes, int n_in,
                              void* d_out, int out_size, void* d_ws, size_t ws_size,
                              hipStream_t stream) {
    const float* f    = (const float*)d_in[0];   // (8,256,640)
    const float* p    = (const float*)d_in[1];   // (8,64,640)
    const float* W    = (const float*)d_in[2];   // (1024,640)
    const float* bias = (const float*)d_in[3];   // (1024)
    float* out = (float*)d_out;                  // (8,256,64,1024) fp32

    const int grid = (MDIM / 128) * (VDIM / 128);  // 8192 blocks

    const size_t wb_bytes = (size_t)VDIM * HDIM * sizeof(ushort);   // 1.25 MB
    const size_t h_bytes  = (size_t)MDIM * HDIM * sizeof(ushort);   // 160 MB

    if (ws_size >= wb_bytes + h_bytes) {
        ushort* Wb = (ushort*)d_ws;
        ushort* h  = (ushort*)((char*)d_ws + wb_bytes);  // 256B-aligned
        cvt_w_kernel<<<(VDIM * HDIM) / 1024, 256, 0, stream>>>(W, Wb);
        build_h_kernel<<<MDIM / 32, 256, 0, stream>>>(f, p, h);
        hgemm_kernel<<<grid, 256, 0, stream>>>(h, Wb, bias, out);
    } else if (ws_size >= wb_bytes) {
        ushort* Wb = (ushort*)d_ws;
        cvt_w_kernel<<<(VDIM * HDIM) / 1024, 256, 0, stream>>>(W, Wb);
        joint_gemm_kernel<true><<<grid, 256, 0, stream>>>(f, p, W, Wb, bias, out);
    } else {
        joint_gemm_kernel<false><<<grid, 256, 0, stream>>>(f, p, W, nullptr, bias, out);
    }
}

// Round 3
// 409.087 us; speedup vs baseline: 1.0569x; 1.0569x over previous
//
#include <hip/hip_runtime.h>
#include <hip/hip_bf16.h>

// Problem constants
#define BDIM 8
#define TDIM 256
#define UDIM 64
#define HDIM 640
#define VDIM 1024
#define MDIM (BDIM * TDIM * UDIM)   // 131072

// GEMM tiling
#define BM 256
#define BN 256
#define BK 32
#define NT (HDIM / BK)              // 20 K-tiles

typedef __attribute__((ext_vector_type(8))) short short8;   // 8 bf16 (16B)
typedef __attribute__((ext_vector_type(4))) float f32x4;

__device__ __forceinline__ ushort f2bf(float x) {
    union { float f; unsigned int u; } v; v.f = x;
    unsigned int r = (v.u + 0x7fffu + ((v.u >> 16) & 1u)) >> 16;  // RNE
    return (ushort)r;
}

// Prep 1: W (V x H fp32) -> bf16
__global__ void cvt_w_kernel(const float* __restrict__ W, ushort* __restrict__ Wb) {
    int i = (blockIdx.x * 256 + threadIdx.x) * 4;
    f32x4 w = *(const f32x4*)(W + i);
    ushort4 o;
    o.x = f2bf(w[0]); o.y = f2bf(w[1]); o.z = f2bf(w[2]); o.w = f2bf(w[3]);
    *(ushort4*)(Wb + i) = o;
}

// Prep 2: h[m][k] = relu(f[b][t][k] + p[b][u][k]) as bf16
__global__ __launch_bounds__(256) void build_h_kernel(
    const float* __restrict__ f, const float* __restrict__ p,
    ushort* __restrict__ h)
{
    const int tid = threadIdx.x;
    const int row = (blockIdx.x << 5) + (tid >> 3);
    const int j0  = tid & 7;
    const int b = row >> 14;
    const int t = (row >> 6) & (TDIM - 1);
    const int u = row & (UDIM - 1);
    const float* frow = f + (size_t)(b * TDIM + t) * HDIM;
    const float* prow = p + (size_t)(b * UDIM + u) * HDIM;
    ushort* hrow = h + (size_t)row * HDIM;
    #pragma unroll
    for (int it = 0; it < HDIM / 64; ++it) {
        const int k = (j0 + it * 8) * 8;
        f32x4 f0 = *(const f32x4*)(frow + k);
        f32x4 f1 = *(const f32x4*)(frow + k + 4);
        f32x4 p0 = *(const f32x4*)(prow + k);
        f32x4 p1 = *(const f32x4*)(prow + k + 4);
        short8 hv;
        #pragma unroll
        for (int e = 0; e < 4; ++e) {
            float a0 = fmaxf(f0[e] + p0[e], 0.0f);
            float a1 = fmaxf(f1[e] + p1[e], 0.0f);
            hv[e]     = (short)f2bf(a0);
            hv[e + 4] = (short)f2bf(a1);
        }
        *(short8*)(hrow + k) = hv;
    }
}

// 256x256 tile, BK=32, 8 waves (2Mx4N), depth-2 pipelined with counted vmcnt.
// LDS: 2 buffers x (A 256x32 + B 256x32) bf16 = 64 KB.
// Swizzle: 16B-chunk slot = j ^ ((row>>1)&3)  (4 chunks per 64B row).
#define GLDS(srcptr, ldsptr)                                                   \
    __builtin_amdgcn_global_load_lds(                                          \
        (const __attribute__((address_space(1))) void*)(srcptr),               \
        (__attribute__((address_space(3))) void*)(ldsptr), 16, 0, 0)

__global__ __launch_bounds__(512) void hgemm256_kernel(
    const ushort* __restrict__ h,     // (M,H) bf16
    const ushort* __restrict__ Wb,    // (V,H) bf16
    const float* __restrict__ bias,   // (V)
    float* __restrict__ out)          // (M,V) fp32
{
    __shared__ ushort Ash[2][BM * BK];   // 2 x 16 KB
    __shared__ ushort Bsh[2][BN * BK];   // 2 x 16 KB

    const int tid  = threadIdx.x;
    const int lane = tid & 63;
    const int wave = tid >> 6;    // 0..7
    const int wm   = wave >> 2;   // 0..1 -> 128-row half
    const int wn   = wave & 3;    // 0..3 -> 64-col quarter

    // Bijective XCD swizzle: 2048 blocks, 2048%8==0. One XCD walks ntiles
    // fast -> A-panel L2-reused 4x, full Wb (1.25MB) L2-resident.
    const int bid   = blockIdx.x;
    const int work  = (bid & 7) * 256 + (bid >> 3);
    const int mtile = work >> 2;
    const int ntile = work & 3;
    const int m0 = mtile * BM;
    const int v0 = ntile * BN;

    const ushort* hbase = h  + (size_t)m0 * HDIM;
    const ushort* wbase = Wb + (size_t)v0 * HDIM;

    // Staging map: c = it*512 + tid; row=c>>2 (0..255 over 2 rounds); j=c&3.
    // Linear LDS dest slot j holds global chunk j^((row>>1)&3) (pre-swizzled src).
    const int row0 = tid >> 2;
    const int j0   = tid & 3;
    const int jg0  = j0 ^ ((row0 >> 1) & 3);
    const size_t soff0 = (size_t)row0 * HDIM + jg0 * 8;   // + kt*BK at use
    const size_t soff1 = soff0 + (size_t)128 * HDIM;      // row0+128: same jg
    const int u0 = wave * 512;          // (wave*64)*8 ushorts, lane*16B added by HW
    const int u1 = 4096 + wave * 512;   // (512+wave*64)*8

    // Fragment LDS offsets (ushort idx), kt-independent:
    int aoff[8], boff[4];
    #pragma unroll
    for (int mi = 0; mi < 8; ++mi) {
        const int r = wm * 128 + mi * 16 + (lane & 15);
        aoff[mi] = (r * 4 + ((lane >> 4) ^ ((r >> 1) & 3))) * 8;
    }
    #pragma unroll
    for (int ni = 0; ni < 4; ++ni) {
        const int r = wn * 64 + ni * 16 + (lane & 15);
        boff[ni] = (r * 4 + ((lane >> 4) ^ ((r >> 1) & 3))) * 8;
    }

    f32x4 acc[8][4];
    #pragma unroll
    for (int i = 0; i < 8; ++i)
        #pragma unroll
        for (int j = 0; j < 4; ++j)
            acc[i][j] = (f32x4)0.0f;

#define STAGE(kt, bf) do {                                                     \
        GLDS(hbase + soff0 + (kt) * BK, &Ash[bf][u0]);                         \
        GLDS(hbase + soff1 + (kt) * BK, &Ash[bf][u1]);                         \
        GLDS(wbase + soff0 + (kt) * BK, &Bsh[bf][u0]);                         \
        GLDS(wbase + soff1 + (kt) * BK, &Bsh[bf][u1]);                         \
    } while (0)

    STAGE(0, 0);
    STAGE(1, 1);

    for (int kt = 0; kt < NT; ++kt) {
        const int bf = kt & 1;
        // Wait for tile kt's 4 loads (issued >= one full tile-compute ago).
        // Steady state: outstanding = kt's 4 + (kt+1)'s 4 -> vmcnt(4), never 0.
        if (kt + 1 < NT) {
            asm volatile("s_waitcnt vmcnt(4)" ::: "memory");
        } else {
            asm volatile("s_waitcnt vmcnt(0)" ::: "memory");
        }
        __builtin_amdgcn_sched_barrier(0);
        __builtin_amdgcn_s_barrier();           // all waves' tile-kt loads landed
        __builtin_amdgcn_sched_barrier(0);

        const ushort* Ab = &Ash[bf][0];
        const ushort* Bb = &Bsh[bf][0];

        short8 bfr[4];
        #pragma unroll
        for (int ni = 0; ni < 4; ++ni)
            bfr[ni] = *(const short8*)(Bb + boff[ni]);

        __builtin_amdgcn_s_setprio(1);
        #pragma unroll
        for (int mi = 0; mi < 8; ++mi) {
            short8 av = *(const short8*)(Ab + aoff[mi]);
            #pragma unroll
            for (int ni = 0; ni < 4; ++ni)
                acc[mi][ni] = __builtin_amdgcn_mfma_f32_16x16x32_bf16(
                    av, bfr[ni], acc[mi][ni], 0, 0, 0);
        }
        __builtin_amdgcn_s_setprio(0);

        asm volatile("s_waitcnt lgkmcnt(0)" ::: "memory");
        __builtin_amdgcn_sched_barrier(0);
        __builtin_amdgcn_s_barrier();           // all waves done reading buf bf
        __builtin_amdgcn_sched_barrier(0);

        if (kt + 2 < NT) STAGE(kt + 2, bf);     // safe: bf's readers retired
    }
#undef STAGE

    // Epilogue: C/D col = lane&15, row = (lane>>4)*4 + reg
    #pragma unroll
    for (int ni = 0; ni < 4; ++ni) {
        const int col = v0 + wn * 64 + ni * 16 + (lane & 15);
        const float bv = bias[col];
        #pragma unroll
        for (int mi = 0; mi < 8; ++mi) {
            const int rbase = m0 + wm * 128 + mi * 16 + ((lane >> 4) << 2);
            #pragma unroll
            for (int reg = 0; reg < 4; ++reg) {
                out[(size_t)(rbase + reg) * VDIM + col] = acc[mi][ni][reg] + bv;
            }
        }
    }
}

// ---------------- fallback fused kernel (round-1 verified) ----------------
template <bool USE_WB>
__global__ __launch_bounds__(256) void joint_gemm_kernel(
    const float* __restrict__ f, const float* __restrict__ p,
    const float* __restrict__ Wf, const ushort* __restrict__ Wb,
    const float* __restrict__ bias, float* __restrict__ out)
{
    __shared__ ushort Alds[128 * 64];
    __shared__ ushort Blds[128 * 64];

    const int tid  = threadIdx.x;
    const int lane = tid & 63;
    const int wave = tid >> 6;
    const int wm   = wave >> 1;
    const int wn   = wave & 1;

    const int bid   = blockIdx.x;
    const int work  = (bid & 7) * 1024 + (bid >> 3);
    const int mtile = work >> 3;
    const int ntile = work & 7;
    const int m0 = mtile * 128;
    const int v0 = ntile * 128;

    const int b  = m0 >> 14;
    const int t0 = (m0 >> 6) & (TDIM - 1);

    const float*  fbase = f + (size_t)(b * TDIM + t0) * HDIM;
    const float*  pbase = p + (size_t)b * UDIM * HDIM;
    const ushort* wbbase = Wb + (size_t)v0 * HDIM;
    const float*  wfbase = Wf + (size_t)v0 * HDIM;

    f32x4 acc[4][4];
    #pragma unroll
    for (int i = 0; i < 4; ++i)
        #pragma unroll
        for (int j = 0; j < 4; ++j)
            acc[i][j] = (f32x4)0.0f;

    for (int kt = 0; kt < HDIM / 64; ++kt) {
        const int k0 = kt * 64;
        __syncthreads();

        if (USE_WB) {
            #pragma unroll
            for (int it = 0; it < 4; ++it) {
                const int c   = it * 256 + tid;
                const int row = c >> 3;
                const int j   = c & 7;
                const ushort* src = wbbase + row * HDIM + k0 + ((j ^ (row & 7)) << 3);
                GLDS(src, &Blds[(it * 256 + wave * 64) * 8]);
            }
        } else {
            #pragma unroll
            for (int it = 0; it < 4; ++it) {
                const int c   = it * 256 + tid;
                const int row = c >> 3;
                const int j   = c & 7;
                const float* wp = wfbase + row * HDIM + k0 + j * 8;
                f32x4 w0 = *(const f32x4*)wp;
                f32x4 w1 = *(const f32x4*)(wp + 4);
                short8 wv;
                #pragma unroll
                for (int e = 0; e < 4; ++e) {
                    wv[e]     = (short)f2bf(w0[e]);
                    wv[e + 4] = (short)f2bf(w1[e]);
                }
                *(short8*)(&Blds[(row * 8 + (j ^ (row & 7))) * 8]) = wv;
            }
        }

        #pragma unroll
        for (int it = 0; it < 4; ++it) {
            const int c   = it * 256 + tid;
            const int row = c >> 3;
            const int j   = c & 7;
            const float* fp_ = fbase + (row >> 6) * HDIM + k0 + j * 8;
            const float* pp_ = pbase + (row & 63) * HDIM + k0 + j * 8;
            f32x4 f0 = *(const f32x4*)fp_;
            f32x4 f1 = *(const f32x4*)(fp_ + 4);
            f32x4 p0 = *(const f32x4*)pp_;
            f32x4 p1 = *(const f32x4*)(pp_ + 4);
            short8 hv;
            #pragma unroll
            for (int e = 0; e < 4; ++e) {
                float a0 = fmaxf(f0[e] + p0[e], 0.0f);
                float a1 = fmaxf(f1[e] + p1[e], 0.0f);
                hv[e]     = (short)f2bf(a0);
                hv[e + 4] = (short)f2bf(a1);
            }
            *(short8*)(&Alds[(row * 8 + (j ^ (row & 7))) * 8]) = hv;
        }

        __syncthreads();

        #pragma unroll
        for (int ks = 0; ks < 2; ++ks) {
            short8 afr[4], bfr[4];
            #pragma unroll
            for (int mi = 0; mi < 4; ++mi) {
                const int r = wm * 64 + mi * 16 + (lane & 15);
                const int j = ks * 4 + (lane >> 4);
                afr[mi] = *(const short8*)(&Alds[(r * 8 + (j ^ (r & 7))) * 8]);
            }
            #pragma unroll
            for (int ni = 0; ni < 4; ++ni) {
                const int r = wn * 64 + ni * 16 + (lane & 15);
                const int j = ks * 4 + (lane >> 4);
                bfr[ni] = *(const short8*)(&Blds[(r * 8 + (j ^ (r & 7))) * 8]);
            }
            #pragma unroll
            for (int mi = 0; mi < 4; ++mi)
                #pragma unroll
                for (int ni = 0; ni < 4; ++ni)
                    acc[mi][ni] = __builtin_amdgcn_mfma_f32_16x16x32_bf16(
                        afr[mi], bfr[ni], acc[mi][ni], 0, 0, 0);
        }
    }

    #pragma unroll
    for (int ni = 0; ni < 4; ++ni) {
        const int col = v0 + wn * 64 + ni * 16 + (lane & 15);
        const float bv = bias[col];
        #pragma unroll
        for (int mi = 0; mi < 4; ++mi) {
            const int rbase = m0 + wm * 64 + mi * 16 + ((lane >> 4) << 2);
            #pragma unroll
            for (int reg = 0; reg < 4; ++reg) {
                out[(size_t)(rbase + reg) * VDIM + col] = acc[mi][ni][reg] + bv;
            }
        }
    }
}

extern "C" void kernel_launch(void* const* d_in, const int* in_sizes, int n_in,
                              void* d_out, int out_size, void* d_ws, size_t ws_size,
                              hipStream_t stream) {
    const float* f    = (const float*)d_in[0];   // (8,256,640)
    const float* p    = (const float*)d_in[1];   // (8,64,640)
    const float* W    = (const float*)d_in[2];   // (1024,640)
    const float* bias = (const float*)d_in[3];   // (1024)
    float* out = (float*)d_out;                  // (8,256,64,1024) fp32

    const size_t wb_bytes = (size_t)VDIM * HDIM * sizeof(ushort);   // 1.25 MB
    const size_t h_bytes  = (size_t)MDIM * HDIM * sizeof(ushort);   // 160 MB

    if (ws_size >= wb_bytes + h_bytes) {
        ushort* Wb = (ushort*)d_ws;
        ushort* h  = (ushort*)((char*)d_ws + wb_bytes);
        cvt_w_kernel<<<(VDIM * HDIM) / 1024, 256, 0, stream>>>(W, Wb);
        build_h_kernel<<<MDIM / 32, 256, 0, stream>>>(f, p, h);
        const int grid = (MDIM / BM) * (VDIM / BN);   // 2048
        hgemm256_kernel<<<grid, 512, 0, stream>>>(h, Wb, bias, out);
    } else if (ws_size >= wb_bytes) {
        ushort* Wb = (ushort*)d_ws;
        cvt_w_kernel<<<(VDIM * HDIM) / 1024, 256, 0, stream>>>(W, Wb);
        joint_gemm_kernel<true><<<(MDIM / 128) * (VDIM / 128), 256, 0, stream>>>(
            f, p, W, Wb, bias, out);
    } else {
        joint_gemm_kernel<false><<<(MDIM / 128) * (VDIM / 128), 256, 0, stream>>>(
            f, p, W, nullptr, bias, out);
    }
}